// Round 1
// baseline (211.119 us; speedup 1.0000x reference)
//
#include <hip/hip_runtime.h>

// Problem dims: B=16, Q=64, K=512, DQ=DK=DV=512, H=256
#define LOG2E 1.4426950408889634f
#define TWO_LOG2E 2.8853900817779268f

// ---------------------------------------------------------------------------
// Kernel 1a: qp[1024][256] = queries[1024][512] @ Wq[512][256]   (fp32 tiled)
// 64x64 tile, 256 threads, 4x4 micro-tile, K-chunk 32.
// ---------------------------------------------------------------------------
__global__ __launch_bounds__(256) void proj_q_kernel(const float* __restrict__ A,
                                                     const float* __restrict__ W,
                                                     float* __restrict__ C) {
    __shared__ float As[32][68];   // [d][m], padded stride 68 (16B-aligned rows)
    __shared__ float Ws[32][68];   // [d][n]
    const int t  = threadIdx.x;
    const int m0 = blockIdx.x * 64;
    const int n0 = blockIdx.y * 64;
    const int mr = (t & 15) * 4;
    const int nr = (t >> 4) * 4;

    float acc[4][4];
#pragma unroll
    for (int i = 0; i < 4; ++i)
#pragma unroll
        for (int j = 0; j < 4; ++j) acc[i][j] = 0.0f;

    for (int d0 = 0; d0 < 512; d0 += 32) {
        // stage A tile transposed into LDS
#pragma unroll
        for (int p = 0; p < 2; ++p) {
            int u  = t + p * 256;          // 0..511
            int m  = u >> 3;               // 0..63
            int d4 = (u & 7) * 4;          // 0..28
            float4 a = *reinterpret_cast<const float4*>(&A[(size_t)(m0 + m) * 512 + d0 + d4]);
            As[d4 + 0][m] = a.x; As[d4 + 1][m] = a.y;
            As[d4 + 2][m] = a.z; As[d4 + 3][m] = a.w;
        }
        // stage W tile
#pragma unroll
        for (int p = 0; p < 2; ++p) {
            int u  = t + p * 256;
            int d  = u >> 4;               // 0..31
            int n4 = (u & 15) * 4;         // 0..60
            *reinterpret_cast<float4*>(&Ws[d][n4]) =
                *reinterpret_cast<const float4*>(&W[(size_t)(d0 + d) * 256 + n0 + n4]);
        }
        __syncthreads();
#pragma unroll
        for (int d = 0; d < 32; ++d) {
            float4 a4 = *reinterpret_cast<const float4*>(&As[d][mr]);
            float4 b4 = *reinterpret_cast<const float4*>(&Ws[d][nr]);
            float av[4] = {a4.x, a4.y, a4.z, a4.w};
            float bv[4] = {b4.x, b4.y, b4.z, b4.w};
#pragma unroll
            for (int i = 0; i < 4; ++i)
#pragma unroll
                for (int j = 0; j < 4; ++j)
                    acc[i][j] = fmaf(av[i], bv[j], acc[i][j]);
        }
        __syncthreads();
    }
#pragma unroll
    for (int i = 0; i < 4; ++i) {
        float4 o; o.x = acc[i][0]; o.y = acc[i][1]; o.z = acc[i][2]; o.w = acc[i][3];
        *reinterpret_cast<float4*>(&C[(size_t)(m0 + mr + i) * 256 + n0 + nr]) = o;
    }
}

// ---------------------------------------------------------------------------
// Kernel 1b: kpT[b][h][k] = (keys[b] @ Wk)^T — same GEMM, transposed store via LDS.
// M = 8192 flat (b,k) rows; tile stays within one b (512 % 64 == 0).
// ---------------------------------------------------------------------------
__global__ __launch_bounds__(256) void proj_k_kernel(const float* __restrict__ A,
                                                     const float* __restrict__ W,
                                                     float* __restrict__ CT) {
    __shared__ float smem[4352];   // As[32][68] + Ws[32][68]; reused as Cs[64][68]
    float (*As)[68] = reinterpret_cast<float(*)[68]>(smem);
    float (*Ws)[68] = reinterpret_cast<float(*)[68]>(smem + 2176);
    const int t  = threadIdx.x;
    const int m0 = blockIdx.x * 64;   // flat (b,k) row base
    const int n0 = blockIdx.y * 64;   // h base
    const int mr = (t & 15) * 4;
    const int nr = (t >> 4) * 4;

    float acc[4][4];
#pragma unroll
    for (int i = 0; i < 4; ++i)
#pragma unroll
        for (int j = 0; j < 4; ++j) acc[i][j] = 0.0f;

    for (int d0 = 0; d0 < 512; d0 += 32) {
#pragma unroll
        for (int p = 0; p < 2; ++p) {
            int u  = t + p * 256;
            int m  = u >> 3;
            int d4 = (u & 7) * 4;
            float4 a = *reinterpret_cast<const float4*>(&A[(size_t)(m0 + m) * 512 + d0 + d4]);
            As[d4 + 0][m] = a.x; As[d4 + 1][m] = a.y;
            As[d4 + 2][m] = a.z; As[d4 + 3][m] = a.w;
        }
#pragma unroll
        for (int p = 0; p < 2; ++p) {
            int u  = t + p * 256;
            int d  = u >> 4;
            int n4 = (u & 15) * 4;
            *reinterpret_cast<float4*>(&Ws[d][n4]) =
                *reinterpret_cast<const float4*>(&W[(size_t)(d0 + d) * 256 + n0 + n4]);
        }
        __syncthreads();
#pragma unroll
        for (int d = 0; d < 32; ++d) {
            float4 a4 = *reinterpret_cast<const float4*>(&As[d][mr]);
            float4 b4 = *reinterpret_cast<const float4*>(&Ws[d][nr]);
            float av[4] = {a4.x, a4.y, a4.z, a4.w};
            float bv[4] = {b4.x, b4.y, b4.z, b4.w};
#pragma unroll
            for (int i = 0; i < 4; ++i)
#pragma unroll
                for (int j = 0; j < 4; ++j)
                    acc[i][j] = fmaf(av[i], bv[j], acc[i][j]);
        }
        __syncthreads();   // also protects smem reuse as Cs below
    }
    // transpose in LDS: Cs[n(h)][m(k)]
    float (*Cs)[68] = reinterpret_cast<float(*)[68]>(smem);
#pragma unroll
    for (int i = 0; i < 4; ++i)
#pragma unroll
        for (int j = 0; j < 4; ++j)
            Cs[nr + j][mr + i] = acc[i][j];
    __syncthreads();

    const int b  = m0 >> 9;        // m0 / 512
    const int k0 = m0 & 511;
    const int h0 = n0;
#pragma unroll
    for (int p = 0; p < 4; ++p) {
        int u  = t + p * 256;      // 0..1023
        int hr = u >> 4;           // 0..63
        int k4 = (u & 15) * 4;     // 0..60
        *reinterpret_cast<float4*>(&CT[(size_t)b * 131072 + (size_t)(h0 + hr) * 512 + k0 + k4]) =
            *reinterpret_cast<const float4*>(&Cs[hr][k4]);
    }
}

// ---------------------------------------------------------------------------
// Kernel 2: scores + masked softmax -> attn[b][q][k]
// Block = (b, 2 q's), 256 threads; thread covers 4 consecutive k (float4 from kpT).
// tanh(x) = 1 - 2*rcp(1+exp2(2x*log2e));  score = sum(Wv) + sum(-2*Wv[h]*r_h)
// ---------------------------------------------------------------------------
__global__ __launch_bounds__(256) void score_softmax_kernel(
        const float* __restrict__ qp, const float* __restrict__ kpT,
        const float* __restrict__ Wv, const int* __restrict__ valid_lens,
        float* __restrict__ attn) {
    __shared__ float qs[2][256];
    __shared__ float wv2[256];
    __shared__ float wsum_s;
    __shared__ float redm[4];
    __shared__ float redl[4];

    const int t  = threadIdx.x;
    const int b  = blockIdx.y;
    const int q0 = blockIdx.x * 2;

    wv2[t]   = -2.0f * Wv[t];
    qs[0][t] = qp[(size_t)(b * 64 + q0) * 256 + t];
    qs[1][t] = qp[(size_t)(b * 64 + q0 + 1) * 256 + t];
    __syncthreads();
    if (t == 0) {
        float s = 0.0f;
        for (int h = 0; h < 256; ++h) s += wv2[h];
        wsum_s = -0.5f * s;   // = sum(Wv)
    }
    __syncthreads();
    const float wsum = wsum_s;

    const int ql = t >> 7;          // which q of the pair
    const int kf = t & 127;         // float4 index over k (k = 4*kf..4*kf+3)
    const int vl = valid_lens[b];
    const float* qrow = qs[ql];
    const float4* kp4 = reinterpret_cast<const float4*>(kpT) + (size_t)b * 256 * 128 + kf;

    float s0 = 0.f, s1 = 0.f, s2 = 0.f, s3 = 0.f;
#pragma unroll 4
    for (int h = 0; h < 256; ++h) {
        const float4 kv = kp4[h * 128];
        const float qh = qrow[h];
        const float w2 = wv2[h];
        float x0 = (qh + kv.x) * TWO_LOG2E;
        float x1 = (qh + kv.y) * TWO_LOG2E;
        float x2 = (qh + kv.z) * TWO_LOG2E;
        float x3 = (qh + kv.w) * TWO_LOG2E;
        float r0 = __builtin_amdgcn_rcpf(1.0f + __builtin_amdgcn_exp2f(x0));
        float r1 = __builtin_amdgcn_rcpf(1.0f + __builtin_amdgcn_exp2f(x1));
        float r2 = __builtin_amdgcn_rcpf(1.0f + __builtin_amdgcn_exp2f(x2));
        float r3 = __builtin_amdgcn_rcpf(1.0f + __builtin_amdgcn_exp2f(x3));
        s0 = fmaf(w2, r0, s0);
        s1 = fmaf(w2, r1, s1);
        s2 = fmaf(w2, r2, s2);
        s3 = fmaf(w2, r3, s3);
    }
    float s4[4] = {s0 + wsum, s1 + wsum, s2 + wsum, s3 + wsum};
    const int kk = kf * 4;
#pragma unroll
    for (int i = 0; i < 4; ++i)
        if (kk + i >= vl) s4[i] = -1e6f;

    // max over 512 k (2 waves per q)
    float m = fmaxf(fmaxf(s4[0], s4[1]), fmaxf(s4[2], s4[3]));
#pragma unroll
    for (int off = 32; off > 0; off >>= 1) m = fmaxf(m, __shfl_xor(m, off));
    const int w = t >> 6;
    if ((t & 63) == 0) redm[w] = m;
    __syncthreads();
    m = fmaxf(redm[ql * 2], redm[ql * 2 + 1]);

    float p[4];
    float l = 0.0f;
#pragma unroll
    for (int i = 0; i < 4; ++i) {
        p[i] = __builtin_amdgcn_exp2f((s4[i] - m) * LOG2E);  // masked -> exp2(-1.4e6) = 0
        l += p[i];
    }
#pragma unroll
    for (int off = 32; off > 0; off >>= 1) l += __shfl_xor(l, off);
    if ((t & 63) == 0) redl[w] = l;
    __syncthreads();
    l = redl[ql * 2] + redl[ql * 2 + 1];
    const float inv = 1.0f / l;

    float4 o; o.x = p[0] * inv; o.y = p[1] * inv; o.z = p[2] * inv; o.w = p[3] * inv;
    reinterpret_cast<float4*>(attn)[(size_t)(b * 64 + q0 + ql) * 128 + kf] = o;
}

// ---------------------------------------------------------------------------
// Kernel 3: out[b][q][v] = attn[b][q][:] @ values[b][:][v]
// Block = (b, 16 q, 128 v), 256 threads; attn tile staged in LDS.
// ---------------------------------------------------------------------------
__global__ __launch_bounds__(256) void pv_kernel(const float* __restrict__ attn,
                                                 const float* __restrict__ values,
                                                 float* __restrict__ out) {
    __shared__ float attnS[16][516];   // padded stride 516 (16B-aligned rows)
    const int t  = threadIdx.x;
    const int b  = blockIdx.z;
    const int q0 = blockIdx.y * 16;
    const int v4b = blockIdx.x * 32;   // float4 col base (128 floats)

    const float4* a4 = reinterpret_cast<const float4*>(attn) + (size_t)(b * 64 + q0) * 128;
#pragma unroll
    for (int p = 0; p < 8; ++p) {
        int u  = t + p * 256;          // 0..2047
        int qr = u >> 7;               // 0..15
        int c4 = u & 127;              // 0..127
        *reinterpret_cast<float4*>(&attnS[qr][c4 * 4]) = a4[qr * 128 + c4];
    }
    __syncthreads();

    const int qa = (t >> 5) * 2;       // 0,2,..,14
    const int vc = v4b + (t & 31);     // float4 col index into 128-f4 row
    const float4* val4 = reinterpret_cast<const float4*>(values) + (size_t)b * 512 * 128 + vc;

    float a0x = 0.f, a0y = 0.f, a0z = 0.f, a0w = 0.f;
    float a1x = 0.f, a1y = 0.f, a1z = 0.f, a1w = 0.f;
    for (int k = 0; k < 512; k += 4) {
        float4 t0 = *reinterpret_cast<const float4*>(&attnS[qa][k]);
        float4 t1 = *reinterpret_cast<const float4*>(&attnS[qa + 1][k]);
        float a0_[4] = {t0.x, t0.y, t0.z, t0.w};
        float a1_[4] = {t1.x, t1.y, t1.z, t1.w};
#pragma unroll
        for (int j = 0; j < 4; ++j) {
            float4 vv = val4[(size_t)(k + j) * 128];
            a0x = fmaf(a0_[j], vv.x, a0x); a0y = fmaf(a0_[j], vv.y, a0y);
            a0z = fmaf(a0_[j], vv.z, a0z); a0w = fmaf(a0_[j], vv.w, a0w);
            a1x = fmaf(a1_[j], vv.x, a1x); a1y = fmaf(a1_[j], vv.y, a1y);
            a1z = fmaf(a1_[j], vv.z, a1z); a1w = fmaf(a1_[j], vv.w, a1w);
        }
    }
    float4* o4 = reinterpret_cast<float4*>(out);
    float4 o0; o0.x = a0x; o0.y = a0y; o0.z = a0z; o0.w = a0w;
    float4 o1; o1.x = a1x; o1.y = a1y; o1.z = a1z; o1.w = a1w;
    o4[(size_t)(b * 64 + q0 + qa) * 128 + vc]     = o0;
    o4[(size_t)(b * 64 + q0 + qa + 1) * 128 + vc] = o1;
}

// ---------------------------------------------------------------------------
extern "C" void kernel_launch(void* const* d_in, const int* in_sizes, int n_in,
                              void* d_out, int out_size, void* d_ws, size_t ws_size,
                              hipStream_t stream) {
    (void)in_sizes; (void)n_in; (void)out_size; (void)ws_size;
    const float* queries    = (const float*)d_in[0];   // [16,64,512]
    const float* keys       = (const float*)d_in[1];   // [16,512,512]
    const float* values     = (const float*)d_in[2];   // [16,512,512]
    const int*   valid_lens = (const int*)d_in[3];     // [16]
    const float* Wq         = (const float*)d_in[4];   // [512,256]
    const float* Wk         = (const float*)d_in[5];   // [512,256]
    const float* Wv         = (const float*)d_in[6];   // [256]
    float* out = (float*)d_out;                        // [16,64,512]

    float* ws   = (float*)d_ws;
    float* qp   = ws;                        // [1024][256]        1 MB
    float* kpT  = ws + 262144;               // [16][256][512]     8 MB
    float* attn = ws + 262144 + 2097152;     // [16][64][512]      2 MB

    hipLaunchKernelGGL(proj_q_kernel, dim3(16, 4), dim3(256), 0, stream, queries, Wq, qp);
    hipLaunchKernelGGL(proj_k_kernel, dim3(128, 4), dim3(256), 0, stream, keys, Wk, kpT);
    hipLaunchKernelGGL(score_softmax_kernel, dim3(32, 16), dim3(256), 0, stream,
                       qp, kpT, Wv, valid_lens, attn);
    hipLaunchKernelGGL(pv_kernel, dim3(4, 4, 16), dim3(256), 0, stream, attn, values, out);
}

// Round 2
// 184.905 us; speedup vs baseline: 1.1418x; 1.1418x over previous
//
#include <hip/hip_runtime.h>

// Problem dims: B=16, Q=64, K=512, DQ=DK=DV=512, H=256
#define LOG2E 1.4426950408889634f
#define TWO_LOG2E 2.8853900817779268f

__device__ __forceinline__ float e2x(float v) {
    // exp2(2*log2(e)*v) == e^{2v}
    return __builtin_amdgcn_exp2f(v * TWO_LOG2E);
}

// ---------------------------------------------------------------------------
// Kernel 1a: Eq[1024][256] = exp2(c * (queries[1024][512] @ Wq[512][256]))
// 64x64 tile, 256 threads, 4x4 micro-tile, K-chunk 32.
// ---------------------------------------------------------------------------
__global__ __launch_bounds__(256) void proj_q_kernel(const float* __restrict__ A,
                                                     const float* __restrict__ W,
                                                     float* __restrict__ C) {
    __shared__ float As[32][68];
    __shared__ float Ws[32][68];
    const int t  = threadIdx.x;
    const int m0 = blockIdx.x * 64;
    const int n0 = blockIdx.y * 64;
    const int mr = (t & 15) * 4;
    const int nr = (t >> 4) * 4;

    float acc[4][4];
#pragma unroll
    for (int i = 0; i < 4; ++i)
#pragma unroll
        for (int j = 0; j < 4; ++j) acc[i][j] = 0.0f;

    for (int d0 = 0; d0 < 512; d0 += 32) {
#pragma unroll
        for (int p = 0; p < 2; ++p) {
            int u  = t + p * 256;
            int m  = u >> 3;
            int d4 = (u & 7) * 4;
            float4 a = *reinterpret_cast<const float4*>(&A[(size_t)(m0 + m) * 512 + d0 + d4]);
            As[d4 + 0][m] = a.x; As[d4 + 1][m] = a.y;
            As[d4 + 2][m] = a.z; As[d4 + 3][m] = a.w;
        }
#pragma unroll
        for (int p = 0; p < 2; ++p) {
            int u  = t + p * 256;
            int d  = u >> 4;
            int n4 = (u & 15) * 4;
            *reinterpret_cast<float4*>(&Ws[d][n4]) =
                *reinterpret_cast<const float4*>(&W[(size_t)(d0 + d) * 256 + n0 + n4]);
        }
        __syncthreads();
#pragma unroll
        for (int d = 0; d < 32; ++d) {
            float4 a4 = *reinterpret_cast<const float4*>(&As[d][mr]);
            float4 b4 = *reinterpret_cast<const float4*>(&Ws[d][nr]);
            float av[4] = {a4.x, a4.y, a4.z, a4.w};
            float bv[4] = {b4.x, b4.y, b4.z, b4.w};
#pragma unroll
            for (int i = 0; i < 4; ++i)
#pragma unroll
                for (int j = 0; j < 4; ++j)
                    acc[i][j] = fmaf(av[i], bv[j], acc[i][j]);
        }
        __syncthreads();
    }
#pragma unroll
    for (int i = 0; i < 4; ++i) {
        float4 o;
        o.x = e2x(acc[i][0]); o.y = e2x(acc[i][1]);
        o.z = e2x(acc[i][2]); o.w = e2x(acc[i][3]);
        *reinterpret_cast<float4*>(&C[(size_t)(m0 + mr + i) * 256 + n0 + nr]) = o;
    }
}

// ---------------------------------------------------------------------------
// Kernel 1b: Ekp[b][h2][k][2] = exp2(c * (keys[b] @ Wk)^T), h-pair interleaved.
// Same GEMM; epilogue transposes in LDS, applies exp2, writes pair layout.
// ---------------------------------------------------------------------------
__global__ __launch_bounds__(256) void proj_k_kernel(const float* __restrict__ A,
                                                     const float* __restrict__ W,
                                                     float* __restrict__ CT) {
    __shared__ float smem[4352];   // As[32][68] + Ws[32][68]; reused as Cs[64][68]
    float (*As)[68] = reinterpret_cast<float(*)[68]>(smem);
    float (*Ws)[68] = reinterpret_cast<float(*)[68]>(smem + 2176);
    const int t  = threadIdx.x;
    const int m0 = blockIdx.x * 64;   // flat (b,k) row base
    const int n0 = blockIdx.y * 64;   // h base
    const int mr = (t & 15) * 4;
    const int nr = (t >> 4) * 4;

    float acc[4][4];
#pragma unroll
    for (int i = 0; i < 4; ++i)
#pragma unroll
        for (int j = 0; j < 4; ++j) acc[i][j] = 0.0f;

    for (int d0 = 0; d0 < 512; d0 += 32) {
#pragma unroll
        for (int p = 0; p < 2; ++p) {
            int u  = t + p * 256;
            int m  = u >> 3;
            int d4 = (u & 7) * 4;
            float4 a = *reinterpret_cast<const float4*>(&A[(size_t)(m0 + m) * 512 + d0 + d4]);
            As[d4 + 0][m] = a.x; As[d4 + 1][m] = a.y;
            As[d4 + 2][m] = a.z; As[d4 + 3][m] = a.w;
        }
#pragma unroll
        for (int p = 0; p < 2; ++p) {
            int u  = t + p * 256;
            int d  = u >> 4;
            int n4 = (u & 15) * 4;
            *reinterpret_cast<float4*>(&Ws[d][n4]) =
                *reinterpret_cast<const float4*>(&W[(size_t)(d0 + d) * 256 + n0 + n4]);
        }
        __syncthreads();
#pragma unroll
        for (int d = 0; d < 32; ++d) {
            float4 a4 = *reinterpret_cast<const float4*>(&As[d][mr]);
            float4 b4 = *reinterpret_cast<const float4*>(&Ws[d][nr]);
            float av[4] = {a4.x, a4.y, a4.z, a4.w};
            float bv[4] = {b4.x, b4.y, b4.z, b4.w};
#pragma unroll
            for (int i = 0; i < 4; ++i)
#pragma unroll
                for (int j = 0; j < 4; ++j)
                    acc[i][j] = fmaf(av[i], bv[j], acc[i][j]);
        }
        __syncthreads();   // also protects smem reuse as Cs below
    }
    // transpose in LDS: Cs[n(h)][m(k)]
    float (*Cs)[68] = reinterpret_cast<float(*)[68]>(smem);
#pragma unroll
    for (int i = 0; i < 4; ++i)
#pragma unroll
        for (int j = 0; j < 4; ++j)
            Cs[nr + j][mr + i] = acc[i][j];
    __syncthreads();

    const int b      = m0 >> 9;
    const int k0h    = (m0 & 511) >> 1;  // k0/2 in float4-pair units
    const int h2base = n0 >> 1;
    float4* out4 = reinterpret_cast<float4*>(CT);
#pragma unroll
    for (int p = 0; p < 4; ++p) {
        int u   = t + p * 256;       // 0..1023
        int h2r = u >> 5;            // 0..31
        int kk  = (u & 31) * 2;      // 0..62, step 2
        float4 o;
        o.x = e2x(Cs[2 * h2r    ][kk    ]);
        o.y = e2x(Cs[2 * h2r + 1][kk    ]);
        o.z = e2x(Cs[2 * h2r    ][kk + 1]);
        o.w = e2x(Cs[2 * h2r + 1][kk + 1]);
        out4[(size_t)b * 32768 + (size_t)(h2base + h2r) * 256 + k0h + (u & 31)] = o;
    }
}

// ---------------------------------------------------------------------------
// Kernel 2: scores + masked softmax -> attn[b][q][k]
// Block = (b, q-pair), 256 threads; thread covers k=2t,2t+1 for BOTH q's.
// tanh = 1 - 2/(1+Eq*Ek); softmax shift-invariance drops the Σwv constant.
// h-pairing: w0/a0 + w1/a1 = (w0*a1 + w1*a0) * rcp(a0*a1)  (1 rcp / 2 elems)
// ---------------------------------------------------------------------------
__global__ __launch_bounds__(256) void score_softmax_kernel(
        const float* __restrict__ Eq, const float* __restrict__ Ekp,
        const float* __restrict__ Wv, const int* __restrict__ valid_lens,
        float* __restrict__ attn) {
    __shared__ float redmA[4], redmB[4], redlA[4], redlB[4];

    const int t  = threadIdx.x;
    const int bq = blockIdx.x;        // 0..511
    const int b  = bq >> 5;
    const int q0 = (bq & 31) * 2;

    const float* eqA = Eq + (size_t)(b * 64 + q0) * 256;
    const float* eqB = eqA + 256;
    const float4* ek4 = reinterpret_cast<const float4*>(Ekp) + (size_t)b * 32768 + t;

    float accA0 = 0.f, accA1 = 0.f, accB0 = 0.f, accB1 = 0.f;
#pragma unroll 4
    for (int h2 = 0; h2 < 128; ++h2) {
        const float4 ek = ek4[h2 * 256];   // (Ek[h0][k0],Ek[h1][k0],Ek[h0][k1],Ek[h1][k1])
        const float w0 = Wv[2 * h2];
        const float w1 = Wv[2 * h2 + 1];
        {
            const float e0 = eqA[2 * h2], e1 = eqA[2 * h2 + 1];
            float a00 = fmaf(e0, ek.x, 1.0f);
            float a10 = fmaf(e1, ek.y, 1.0f);
            float a01 = fmaf(e0, ek.z, 1.0f);
            float a11 = fmaf(e1, ek.w, 1.0f);
            float d0 = a00 * a10, d1 = a01 * a11;
            float n0 = fmaf(w1, a00, w0 * a10);
            float n1 = fmaf(w1, a01, w0 * a11);
            accA0 = fmaf(n0, __builtin_amdgcn_rcpf(d0), accA0);
            accA1 = fmaf(n1, __builtin_amdgcn_rcpf(d1), accA1);
        }
        {
            const float e0 = eqB[2 * h2], e1 = eqB[2 * h2 + 1];
            float a00 = fmaf(e0, ek.x, 1.0f);
            float a10 = fmaf(e1, ek.y, 1.0f);
            float a01 = fmaf(e0, ek.z, 1.0f);
            float a11 = fmaf(e1, ek.w, 1.0f);
            float d0 = a00 * a10, d1 = a01 * a11;
            float n0 = fmaf(w1, a00, w0 * a10);
            float n1 = fmaf(w1, a01, w0 * a11);
            accB0 = fmaf(n0, __builtin_amdgcn_rcpf(d0), accB0);
            accB1 = fmaf(n1, __builtin_amdgcn_rcpf(d1), accB1);
        }
    }
    // scores (shifted by -Σwv, softmax-invariant)
    float sA0 = -2.0f * accA0, sA1 = -2.0f * accA1;
    float sB0 = -2.0f * accB0, sB1 = -2.0f * accB1;
    const int vl = valid_lens[b];
    const int k0 = 2 * t;
    if (k0     >= vl) { sA0 = -1e6f; sB0 = -1e6f; }
    if (k0 + 1 >= vl) { sA1 = -1e6f; sB1 = -1e6f; }

    const int w = t >> 6;
    // block-wide max per q
    float mA = fmaxf(sA0, sA1);
    float mB = fmaxf(sB0, sB1);
#pragma unroll
    for (int off = 32; off > 0; off >>= 1) {
        mA = fmaxf(mA, __shfl_xor(mA, off));
        mB = fmaxf(mB, __shfl_xor(mB, off));
    }
    if ((t & 63) == 0) { redmA[w] = mA; redmB[w] = mB; }
    __syncthreads();
    mA = fmaxf(fmaxf(redmA[0], redmA[1]), fmaxf(redmA[2], redmA[3]));
    mB = fmaxf(fmaxf(redmB[0], redmB[1]), fmaxf(redmB[2], redmB[3]));

    float pA0 = __builtin_amdgcn_exp2f((sA0 - mA) * LOG2E);
    float pA1 = __builtin_amdgcn_exp2f((sA1 - mA) * LOG2E);
    float pB0 = __builtin_amdgcn_exp2f((sB0 - mB) * LOG2E);
    float pB1 = __builtin_amdgcn_exp2f((sB1 - mB) * LOG2E);
    float lA = pA0 + pA1, lB = pB0 + pB1;
#pragma unroll
    for (int off = 32; off > 0; off >>= 1) {
        lA += __shfl_xor(lA, off);
        lB += __shfl_xor(lB, off);
    }
    if ((t & 63) == 0) { redlA[w] = lA; redlB[w] = lB; }
    __syncthreads();
    lA = (redlA[0] + redlA[1]) + (redlA[2] + redlA[3]);
    lB = (redlB[0] + redlB[1]) + (redlB[2] + redlB[3]);
    const float invA = 1.0f / lA;
    const float invB = 1.0f / lB;

    float2* attn2 = reinterpret_cast<float2*>(attn);
    float2 oA; oA.x = pA0 * invA; oA.y = pA1 * invA;
    float2 oB; oB.x = pB0 * invB; oB.y = pB1 * invB;
    attn2[(size_t)(b * 64 + q0) * 256 + t]       = oA;
    attn2[(size_t)(b * 64 + q0 + 1) * 256 + t]   = oB;
}

// ---------------------------------------------------------------------------
// Kernel 3: out[b][q][v] = attn[b][q][:] @ values[b][:][v]   (unchanged)
// ---------------------------------------------------------------------------
__global__ __launch_bounds__(256) void pv_kernel(const float* __restrict__ attn,
                                                 const float* __restrict__ values,
                                                 float* __restrict__ out) {
    __shared__ float attnS[16][516];
    const int t  = threadIdx.x;
    const int b  = blockIdx.z;
    const int q0 = blockIdx.y * 16;
    const int v4b = blockIdx.x * 32;

    const float4* a4 = reinterpret_cast<const float4*>(attn) + (size_t)(b * 64 + q0) * 128;
#pragma unroll
    for (int p = 0; p < 8; ++p) {
        int u  = t + p * 256;
        int qr = u >> 7;
        int c4 = u & 127;
        *reinterpret_cast<float4*>(&attnS[qr][c4 * 4]) = a4[qr * 128 + c4];
    }
    __syncthreads();

    const int qa = (t >> 5) * 2;
    const int vc = v4b + (t & 31);
    const float4* val4 = reinterpret_cast<const float4*>(values) + (size_t)b * 512 * 128 + vc;

    float a0x = 0.f, a0y = 0.f, a0z = 0.f, a0w = 0.f;
    float a1x = 0.f, a1y = 0.f, a1z = 0.f, a1w = 0.f;
    for (int k = 0; k < 512; k += 4) {
        float4 t0 = *reinterpret_cast<const float4*>(&attnS[qa][k]);
        float4 t1 = *reinterpret_cast<const float4*>(&attnS[qa + 1][k]);
        float a0_[4] = {t0.x, t0.y, t0.z, t0.w};
        float a1_[4] = {t1.x, t1.y, t1.z, t1.w};
#pragma unroll
        for (int j = 0; j < 4; ++j) {
            float4 vv = val4[(size_t)(k + j) * 128];
            a0x = fmaf(a0_[j], vv.x, a0x); a0y = fmaf(a0_[j], vv.y, a0y);
            a0z = fmaf(a0_[j], vv.z, a0z); a0w = fmaf(a0_[j], vv.w, a0w);
            a1x = fmaf(a1_[j], vv.x, a1x); a1y = fmaf(a1_[j], vv.y, a1y);
            a1z = fmaf(a1_[j], vv.z, a1z); a1w = fmaf(a1_[j], vv.w, a1w);
        }
    }
    float4* o4 = reinterpret_cast<float4*>(out);
    float4 o0; o0.x = a0x; o0.y = a0y; o0.z = a0z; o0.w = a0w;
    float4 o1; o1.x = a1x; o1.y = a1y; o1.z = a1z; o1.w = a1w;
    o4[(size_t)(b * 64 + q0 + qa) * 128 + vc]     = o0;
    o4[(size_t)(b * 64 + q0 + qa + 1) * 128 + vc] = o1;
}

// ---------------------------------------------------------------------------
extern "C" void kernel_launch(void* const* d_in, const int* in_sizes, int n_in,
                              void* d_out, int out_size, void* d_ws, size_t ws_size,
                              hipStream_t stream) {
    (void)in_sizes; (void)n_in; (void)out_size; (void)ws_size;
    const float* queries    = (const float*)d_in[0];   // [16,64,512]
    const float* keys       = (const float*)d_in[1];   // [16,512,512]
    const float* values     = (const float*)d_in[2];   // [16,512,512]
    const int*   valid_lens = (const int*)d_in[3];     // [16]
    const float* Wq         = (const float*)d_in[4];   // [512,256]
    const float* Wk         = (const float*)d_in[5];   // [512,256]
    const float* Wv         = (const float*)d_in[6];   // [256]
    float* out = (float*)d_out;                        // [16,64,512]

    float* ws   = (float*)d_ws;
    float* Eq   = ws;                        // [1024][256]              1 MB
    float* Ekp  = ws + 262144;               // [16][128][512][2]        8 MB
    float* attn = ws + 262144 + 2097152;     // [16][64][512]            2 MB

    hipLaunchKernelGGL(proj_q_kernel, dim3(16, 4), dim3(256), 0, stream, queries, Wq, Eq);
    hipLaunchKernelGGL(proj_k_kernel, dim3(128, 4), dim3(256), 0, stream, keys, Wk, Ekp);
    hipLaunchKernelGGL(score_softmax_kernel, dim3(512), dim3(256), 0, stream,
                       Eq, Ekp, Wv, valid_lens, attn);
    hipLaunchKernelGGL(pv_kernel, dim3(4, 4, 16), dim3(256), 0, stream, attn, values, out);
}